// Round 6
// baseline (389.339 us; speedup 1.0000x reference)
//
#include <hip/hip_runtime.h>
#include <hip/hip_bf16.h>

#define NNODES 50000
#define NEDGES 800000
#define CAP 64                       // padded-CSR capacity (max degree ~45, Poisson(16))
#define RSQRT_D 0.17677669529663687f // 1/sqrt(32)

typedef short short8 __attribute__((ext_vector_type(8)));   // 8 bf16 (4 VGPRs)
typedef float f32x4 __attribute__((ext_vector_type(4)));    // MFMA accumulator

__device__ inline unsigned short f2bf(float f) {
    union { float f; unsigned u; } v; v.f = f;
    unsigned r = (v.u + 0x7fff + ((v.u >> 16) & 1)) >> 16;   // round-to-nearest-even
    return (unsigned short)r;
}
__device__ inline float bf2f(unsigned short u) {
    union { unsigned u; float f; } v; v.u = ((unsigned)u) << 16;
    return v.f;
}

// ---------------------------------------------------------------------------
// prep_w: Wt[col][k] bf16 (col 0..415 = Q|K|V|skip), biascat[col] fp32.
// ---------------------------------------------------------------------------
__global__ __launch_bounds__(256) void prep_w(
    const float* __restrict__ Wq, const float* __restrict__ bq,
    const float* __restrict__ Wk, const float* __restrict__ bk,
    const float* __restrict__ Wv, const float* __restrict__ bv,
    const float* __restrict__ Wskip, const float* __restrict__ bskip,
    unsigned short* __restrict__ Wt, float* __restrict__ biascat)
{
    const int col = blockIdx.x;
    const int k = threadIdx.x;
    float v; float b;
    if (col < 128)      { v = Wq[k * 128 + col];          b = bq[col]; }
    else if (col < 256) { v = Wk[k * 128 + col - 128];    b = bk[col - 128]; }
    else if (col < 384) { v = Wv[k * 128 + col - 256];    b = bv[col - 256]; }
    else                { v = Wskip[k * 32 + col - 384];  b = bskip[col - 384]; }
    Wt[col * 256 + k] = f2bf(v);
    if (k == 0) biascat[col] = b;
}

// ---------------------------------------------------------------------------
// gemm_mfma: C[n][c] = y0[n][:] @ Wt[c][:] + bias, split-bf16 (hi+lo) MFMA.
// One wave per 16 rows; grid.y=4 splits the 26 col-tiles 7/7/6/6 so the wave
// supply (12512) exceeds residency capacity (~1792 blocks) and SIMDs refill
// (R5: grid.y=2 gave 27% occupancy, MfmaUtil 7% — latency-bound).
// Outputs: Q bf16 [N][128], KV bf16 [N][256] (K|V), S fp32 [N][32].
// ---------------------------------------------------------------------------
__global__ __launch_bounds__(256) void gemm_mfma(
    const float* __restrict__ x, const float* __restrict__ t,
    const unsigned short* __restrict__ Wt, const float* __restrict__ biascat,
    unsigned short* __restrict__ Qb, unsigned short* __restrict__ KVb,
    float* __restrict__ S)
{
    const int tid = threadIdx.x;
    const int wave = tid >> 6;
    const int lane = tid & 63;
    const int row16 = lane & 15;
    const int quad = lane >> 4;

    const int n0 = blockIdx.x * 64 + wave * 16;    // 16 rows per wave
    const int row = n0 + row16;
    const int by = blockIdx.y;                     // 0..3
    const int ct0 = by * 7 - ((by >= 2) ? (by - 2) : 0);   // 0,7,14,20
    const int nct = (by < 2) ? 7 : 6;

    short8 ahi[8], alo[8];

    #pragma unroll
    for (int kt = 0; kt < 8; ++kt) {
        const int kk = kt * 32 + quad * 8;
        const int kx = (kk < 128) ? kk : (kk - 128);
        float4 f0 = make_float4(0, 0, 0, 0), f1 = f0;
        if (row < NNODES) {
            const float* xr = x + (size_t)row * 128 + kx;
            f0 = *(const float4*)xr;
            f1 = *(const float4*)(xr + 4);
            if (kk >= 128) {
                const float tv = t[row];
                f0.x *= tv; f0.y *= tv; f0.z *= tv; f0.w *= tv;
                f1.x *= tv; f1.y *= tv; f1.z *= tv; f1.w *= tv;
            }
        }
        float fv[8] = { f0.x, f0.y, f0.z, f0.w, f1.x, f1.y, f1.z, f1.w };
        short8 hi, lo;
        #pragma unroll
        for (int j = 0; j < 8; ++j) {
            const unsigned short h = f2bf(fv[j]);
            hi[j] = (short)h;
            lo[j] = (short)f2bf(fv[j] - bf2f(h));
        }
        ahi[kt] = hi; alo[kt] = lo;
    }

    for (int ct = ct0; ct < ct0 + nct; ++ct) {
        const int c = ct * 16 + row16;             // B col / D col for this lane
        const float bias = biascat[c];
        f32x4 acc = {0.f, 0.f, 0.f, 0.f};
        #pragma unroll
        for (int kt = 0; kt < 8; ++kt) {
            const short8 b = *(const short8*)(Wt + (size_t)c * 256 + kt * 32 + quad * 8);
            acc = __builtin_amdgcn_mfma_f32_16x16x32_bf16(alo[kt], b, acc, 0, 0, 0);
            acc = __builtin_amdgcn_mfma_f32_16x16x32_bf16(ahi[kt], b, acc, 0, 0, 0);
        }
        // D: col = row16 (== c), row = quad*4 + i. Branch is wave-uniform
        // (16-col tiles never straddle the 128/256/384 boundaries).
        #pragma unroll
        for (int i = 0; i < 4; ++i) {
            const int m = n0 + quad * 4 + i;
            if (m >= NNODES) continue;
            const float val = acc[i] + bias;
            if (c < 128)      Qb[(size_t)m * 128 + c] = f2bf(val);
            else if (c < 256) KVb[(size_t)m * 256 + (c - 128)] = f2bf(val);
            else if (c < 384) KVb[(size_t)m * 256 + 128 + (c - 256)] = f2bf(val);
            else              S[(size_t)m * 32 + (c - 384)] = val;
        }
    }
}

// ---------------------------------------------------------------------------
// scatter_fill: padded CSR in ONE pass — no histogram, no prefix scan.
// einfo[dst*CAP + pos] = (src, w); cnt[dst] = degree.
// ---------------------------------------------------------------------------
__global__ __launch_bounds__(256) void scatter_fill(
    const int* __restrict__ ei, const float* __restrict__ ew,
    int* __restrict__ cnt, int2* __restrict__ einfo)
{
    const int e = blockIdx.x * 256 + threadIdx.x;
    if (e >= NEDGES) return;
    const int src = ei[e];
    const int dst = ei[NEDGES + e];
    const int pos = atomicAdd(&cnt[dst], 1);
    if (pos < CAP) {
        int2 v; v.x = src; v.y = __float_as_int(ew[e]);
        einfo[(size_t)dst * CAP + pos] = v;
    }
}

// ---------------------------------------------------------------------------
// agg_pass: 32 lanes per node, bf16 gathers, rank-1 edge-attr decomposition:
//   alpha = (q.k)/sqrt(D) + w*(q.We)/sqrt(D) + (q.be)/sqrt(D)
//   agg   = [ sum p*v + (sum p*w)*We + (sum p)*be ] / (sum p + 1e-16)
// then head-mean -> G (N x 32 fp32).
// ---------------------------------------------------------------------------
__global__ __launch_bounds__(256) void agg_pass(
    const int* __restrict__ cnt, const int2* __restrict__ einfo,
    const float* __restrict__ We, const float* __restrict__ be,
    const unsigned short* __restrict__ Qb, const unsigned short* __restrict__ KVb,
    float* __restrict__ G)
{
    const int tid = threadIdx.x;
    const int node = blockIdx.x * 8 + (tid >> 5);
    if (node >= NNODES) return;
    const int l = tid & 31;          // 4 dims per lane; head = l>>3

    const float4 We4 = *(const float4*)(We + l * 4);
    const float4 be4 = *(const float4*)(be + l * 4);

    const ushort4 qu = *(const ushort4*)(Qb + (size_t)node * 128 + l * 4);
    const float q0 = bf2f(qu.x), q1 = bf2f(qu.y), q2 = bf2f(qu.z), q3 = bf2f(qu.w);

    float pwe = q0 * We4.x + q1 * We4.y + q2 * We4.z + q3 * We4.w;
    float pbe = q0 * be4.x + q1 * be4.y + q2 * be4.z + q3 * be4.w;
    pwe += __shfl_xor(pwe, 1); pbe += __shfl_xor(pbe, 1);
    pwe += __shfl_xor(pwe, 2); pbe += __shfl_xor(pbe, 2);
    pwe += __shfl_xor(pwe, 4); pbe += __shfl_xor(pbe, 4);
    const float qWeS = pwe * RSQRT_D;
    const float qbeS = pbe * RSQRT_D;

    float a0 = 0.f, a1 = 0.f, a2 = 0.f, a3 = 0.f;
    float sp = 0.f, spw = 0.f;

    const int deg = min(cnt[node], CAP);
    const int2* ep = einfo + (size_t)node * CAP;
    for (int j = 0; j < deg; ++j) {
        const int2 einf = ep[j];
        const int src = einf.x;
        const float w = __int_as_float(einf.y);
        const ushort4 ku = *(const ushort4*)(KVb + (size_t)src * 256 + l * 4);
        const ushort4 vu = *(const ushort4*)(KVb + (size_t)src * 256 + 128 + l * 4);

        float dot = q0 * bf2f(ku.x) + q1 * bf2f(ku.y)
                  + q2 * bf2f(ku.z) + q3 * bf2f(ku.w);
        dot += __shfl_xor(dot, 1);
        dot += __shfl_xor(dot, 2);
        dot += __shfl_xor(dot, 4);
        const float p = __expf(dot * RSQRT_D + w * qWeS + qbeS);
        sp += p; spw += p * w;
        a0 += p * bf2f(vu.x); a1 += p * bf2f(vu.y);
        a2 += p * bf2f(vu.z); a3 += p * bf2f(vu.w);
    }

    const float inv = 1.f / (sp + 1e-16f);
    a0 = (a0 + spw * We4.x + sp * be4.x) * inv;
    a1 = (a1 + spw * We4.y + sp * be4.y) * inv;
    a2 = (a2 + spw * We4.z + sp * be4.z) * inv;
    a3 = (a3 + spw * We4.w + sp * be4.w) * inv;

    a0 += __shfl_xor(a0, 8);  a1 += __shfl_xor(a1, 8);
    a2 += __shfl_xor(a2, 8);  a3 += __shfl_xor(a3, 8);
    a0 += __shfl_xor(a0, 16); a1 += __shfl_xor(a1, 16);
    a2 += __shfl_xor(a2, 16); a3 += __shfl_xor(a3, 16);

    if (l < 8) {
        float4 g;
        g.x = a0 * 0.25f; g.y = a1 * 0.25f; g.z = a2 * 0.25f; g.w = a3 * 0.25f;
        *(float4*)(G + (size_t)node * 32 + l * 4) = g;
    }
}

// ---------------------------------------------------------------------------
// node_pass: y = tanh(G + S); z = tanh(y @ Wmlp + bmlp);
// out = x*z[:,:128] + z[:,128:]
// ---------------------------------------------------------------------------
__global__ __launch_bounds__(256) void node_pass(
    const float* __restrict__ x,
    const float* __restrict__ G, const float* __restrict__ S,
    const float* __restrict__ Wmlp, const float* __restrict__ bmlp,
    float* __restrict__ out)
{
    __shared__ float Wm[32 * 256];
    __shared__ float bm[256];
    __shared__ float yl[64 * 32];

    const int tid = threadIdx.x;
    for (int i = tid; i < 2048; i += 256)
        *(float4*)&Wm[i * 4] = *(const float4*)(Wmlp + i * 4);
    if (tid < 64)
        *(float4*)&bm[tid * 4] = *(const float4*)(bmlp + tid * 4);

    const int n0 = blockIdx.x * 64;

    for (int idx = tid; idx < 64 * 32; idx += 256) {
        const int nl = idx >> 5, d = idx & 31;
        const int n = n0 + nl;
        float yv = 0.f;
        if (n < NNODES)
            yv = tanhf(G[(size_t)n * 32 + d] + S[(size_t)n * 32 + d]);
        yl[idx] = yv;
    }
    __syncthreads();

    for (int idx = tid; idx < 64 * 128; idx += 256) {
        const int nl = idx >> 7, c = idx & 127;
        const int n = n0 + nl;
        if (n >= NNODES) continue;
        float s1 = bm[c], s2 = bm[c + 128];
        const float* yrow = &yl[nl * 32];
        #pragma unroll
        for (int d = 0; d < 32; ++d) {
            const float yv = yrow[d];
            s1 += yv * Wm[d * 256 + c];
            s2 += yv * Wm[d * 256 + c + 128];
        }
        out[(size_t)n * 128 + c] = x[(size_t)n * 128 + c] * tanhf(s1) + tanhf(s2);
    }
}

// ---------------------------------------------------------------------------
extern "C" void kernel_launch(void* const* d_in, const int* in_sizes, int n_in,
                              void* d_out, int out_size, void* d_ws, size_t ws_size,
                              hipStream_t stream) {
    const float* x     = (const float*)d_in[0];
    const float* t     = (const float*)d_in[1];
    const int*   ei    = (const int*)  d_in[2];
    const float* ew    = (const float*)d_in[3];
    const float* Wq    = (const float*)d_in[4];
    const float* bq    = (const float*)d_in[5];
    const float* Wk    = (const float*)d_in[6];
    const float* bk    = (const float*)d_in[7];
    const float* Wv    = (const float*)d_in[8];
    const float* bv    = (const float*)d_in[9];
    const float* We    = (const float*)d_in[10];
    const float* be    = (const float*)d_in[11];
    const float* Wskip = (const float*)d_in[12];
    const float* bskip = (const float*)d_in[13];
    const float* Wmlp  = (const float*)d_in[14];
    const float* bmlp  = (const float*)d_in[15];

    char* p = (char*)d_ws;
    unsigned short* Qb  = (unsigned short*)p; p += (size_t)NNODES * 128 * 2;
    unsigned short* KVb = (unsigned short*)p; p += (size_t)NNODES * 256 * 2;
    float* S       = (float*)p; p += (size_t)NNODES * 32 * 4;
    float* G       = (float*)p; p += (size_t)NNODES * 32 * 4;
    unsigned short* Wt = (unsigned short*)p; p += 416 * 256 * 2;
    float* biascat = (float*)p; p += 416 * 4;
    int2* einfo    = (int2*)p;  p += (size_t)NNODES * CAP * 8;
    int* cnt       = (int*)p;   p += NNODES * 4;

    hipMemsetAsync(cnt, 0, (size_t)NNODES * sizeof(int), stream);

    prep_w<<<416, 256, 0, stream>>>(Wq, bq, Wk, bk, Wv, bv, Wskip, bskip,
                                    Wt, biascat);

    scatter_fill<<<NEDGES / 256, 256, 0, stream>>>(ei, ew, cnt, einfo);

    dim3 gg((NNODES + 63) / 64, 4);
    gemm_mfma<<<gg, 256, 0, stream>>>(x, t, Wt, biascat, Qb, KVb, S);

    agg_pass<<<NNODES / 8, 256, 0, stream>>>(cnt, einfo, We, be, Qb, KVb, G);

    node_pass<<<(NNODES + 63) / 64, 256, 0, stream>>>(x, G, S, Wmlp, bmlp,
                                                      (float*)d_out);
}

// Round 7
// 389.118 us; speedup vs baseline: 1.0006x; 1.0006x over previous
//
#include <hip/hip_runtime.h>
#include <hip/hip_bf16.h>

#define NNODES 50000
#define NEDGES 800000
#define CAP 64                       // padded-CSR capacity (max degree ~45, Poisson(16))
#define RSQRT_D 0.17677669529663687f // 1/sqrt(32)

typedef short short8 __attribute__((ext_vector_type(8)));   // 8 bf16 (4 VGPRs)
typedef float f32x4 __attribute__((ext_vector_type(4)));    // MFMA accumulator

__device__ inline unsigned short f2bf(float f) {
    union { float f; unsigned u; } v; v.f = f;
    unsigned r = (v.u + 0x7fff + ((v.u >> 16) & 1)) >> 16;   // round-to-nearest-even
    return (unsigned short)r;
}
__device__ inline float bf2f(unsigned short u) {
    union { unsigned u; float f; } v; v.u = ((unsigned)u) << 16;
    return v.f;
}

// ---------------------------------------------------------------------------
// prep_w: Wt[col][k] bf16 (col 0..415 = Q|K|V|skip), biascat[col] fp32.
// ---------------------------------------------------------------------------
__global__ __launch_bounds__(256) void prep_w(
    const float* __restrict__ Wq, const float* __restrict__ bq,
    const float* __restrict__ Wk, const float* __restrict__ bk,
    const float* __restrict__ Wv, const float* __restrict__ bv,
    const float* __restrict__ Wskip, const float* __restrict__ bskip,
    unsigned short* __restrict__ Wt, float* __restrict__ biascat)
{
    const int col = blockIdx.x;
    const int k = threadIdx.x;
    float v; float b;
    if (col < 128)      { v = Wq[k * 128 + col];          b = bq[col]; }
    else if (col < 256) { v = Wk[k * 128 + col - 128];    b = bk[col - 128]; }
    else if (col < 384) { v = Wv[k * 128 + col - 256];    b = bv[col - 256]; }
    else                { v = Wskip[k * 32 + col - 384];  b = bskip[col - 384]; }
    Wt[col * 256 + k] = f2bf(v);
    if (k == 0) biascat[col] = b;
}

// ---------------------------------------------------------------------------
// gemm_mfma: split-bf16 (hi+lo) MFMA, 32 rows/wave, ping-pong B double-buffer.
// R6 lesson: VGPR=76 starved ILP (770 cyc exposed per mem op). Fix:
// __launch_bounds__(256,2) -> ~220 VGPR, A-frags for 32 rows (128 VGPR) +
// two 8-frag B buffers (64 VGPR) so loads stay in flight during MFMA.
// ---------------------------------------------------------------------------
#define LOADB(buf, ct) do {                                                    \
    const int c_ = (ct) * 16 + row16;                                          \
    _Pragma("unroll")                                                          \
    for (int kt_ = 0; kt_ < 8; ++kt_)                                          \
        buf[kt_] = *(const short8*)(Wt + (size_t)c_ * 256 + kt_ * 32 + quad * 8); \
} while (0)

#define DOTILE(buf, ct) do {                                                   \
    const int c_ = (ct) * 16 + row16;                                          \
    f32x4 accA = {0.f, 0.f, 0.f, 0.f};                                         \
    f32x4 accB = {0.f, 0.f, 0.f, 0.f};                                         \
    _Pragma("unroll")                                                          \
    for (int kt_ = 0; kt_ < 8; ++kt_) {                                        \
        accA = __builtin_amdgcn_mfma_f32_16x16x32_bf16(aloA[kt_], buf[kt_], accA, 0, 0, 0); \
        accA = __builtin_amdgcn_mfma_f32_16x16x32_bf16(ahiA[kt_], buf[kt_], accA, 0, 0, 0); \
        accB = __builtin_amdgcn_mfma_f32_16x16x32_bf16(aloB[kt_], buf[kt_], accB, 0, 0, 0); \
        accB = __builtin_amdgcn_mfma_f32_16x16x32_bf16(ahiB[kt_], buf[kt_], accB, 0, 0, 0); \
    }                                                                          \
    const float bias_ = biascat[c_];                                           \
    _Pragma("unroll")                                                          \
    for (int half_ = 0; half_ < 2; ++half_) {                                  \
        _Pragma("unroll")                                                      \
        for (int i_ = 0; i_ < 4; ++i_) {                                       \
            const int m_ = n0 + half_ * 16 + quad * 4 + i_;                    \
            if (m_ < NNODES) {                                                 \
                const float val_ = (half_ ? accB[i_] : accA[i_]) + bias_;      \
                if (c_ < 128)      Qb[(size_t)m_ * 128 + c_] = f2bf(val_);     \
                else if (c_ < 256) KVb[(size_t)m_ * 256 + (c_ - 128)] = f2bf(val_); \
                else if (c_ < 384) KVb[(size_t)m_ * 256 + 128 + (c_ - 256)] = f2bf(val_); \
                else               S[(size_t)m_ * 32 + (c_ - 384)] = val_;     \
            }                                                                  \
        }                                                                      \
    }                                                                          \
} while (0)

__global__ __launch_bounds__(256, 2) void gemm_mfma(
    const float* __restrict__ x, const float* __restrict__ t,
    const unsigned short* __restrict__ Wt, const float* __restrict__ biascat,
    unsigned short* __restrict__ Qb, unsigned short* __restrict__ KVb,
    float* __restrict__ S)
{
    const int tid = threadIdx.x;
    const int wave = tid >> 6;
    const int lane = tid & 63;
    const int row16 = lane & 15;
    const int quad = lane >> 4;

    const int n0 = blockIdx.x * 128 + wave * 32;   // 32 rows per wave
    const int by = blockIdx.y;                     // 0..3
    const int ct0 = by * 7 - ((by >= 2) ? (by - 2) : 0);   // 0,7,14,20
    const int nct = (by < 2) ? 7 : 6;
    const int ctEnd = ct0 + nct;

    short8 ahiA[8], aloA[8], ahiB[8], aloB[8];

    // A fragments for both 16-row halves (y0 = [x, x*t] on the fly)
    #pragma unroll
    for (int half = 0; half < 2; ++half) {
        const int row = n0 + half * 16 + row16;
        const float tv = (row < NNODES) ? t[row] : 0.f;
        #pragma unroll
        for (int kt = 0; kt < 8; ++kt) {
            const int kk = kt * 32 + quad * 8;
            const int kx = (kk < 128) ? kk : (kk - 128);
            float4 f0 = make_float4(0, 0, 0, 0), f1 = f0;
            if (row < NNODES) {
                const float* xr = x + (size_t)row * 128 + kx;
                f0 = *(const float4*)xr;
                f1 = *(const float4*)(xr + 4);
                if (kk >= 128) {
                    f0.x *= tv; f0.y *= tv; f0.z *= tv; f0.w *= tv;
                    f1.x *= tv; f1.y *= tv; f1.z *= tv; f1.w *= tv;
                }
            }
            float fv[8] = { f0.x, f0.y, f0.z, f0.w, f1.x, f1.y, f1.z, f1.w };
            short8 hi, lo;
            #pragma unroll
            for (int j = 0; j < 8; ++j) {
                const unsigned short h = f2bf(fv[j]);
                hi[j] = (short)h;
                lo[j] = (short)f2bf(fv[j] - bf2f(h));
            }
            if (half) { ahiB[kt] = hi; aloB[kt] = lo; }
            else      { ahiA[kt] = hi; aloA[kt] = lo; }
        }
    }

    short8 b0[8], b1[8];
    LOADB(b0, ct0);
    for (int ct = ct0; ct < ctEnd; ct += 2) {
        if (ct + 1 < ctEnd) LOADB(b1, ct + 1);
        DOTILE(b0, ct);
        if (ct + 1 < ctEnd) {
            if (ct + 2 < ctEnd) LOADB(b0, ct + 2);
            DOTILE(b1, ct + 1);
        }
    }
}

// ---------------------------------------------------------------------------
// scatter_fill: padded CSR in ONE pass — no histogram, no prefix scan.
// ---------------------------------------------------------------------------
__global__ __launch_bounds__(256) void scatter_fill(
    const int* __restrict__ ei, const float* __restrict__ ew,
    int* __restrict__ cnt, int2* __restrict__ einfo)
{
    const int e = blockIdx.x * 256 + threadIdx.x;
    if (e >= NEDGES) return;
    const int src = ei[e];
    const int dst = ei[NEDGES + e];
    const int pos = atomicAdd(&cnt[dst], 1);
    if (pos < CAP) {
        int2 v; v.x = src; v.y = __float_as_int(ew[e]);
        einfo[(size_t)dst * CAP + pos] = v;
    }
}

// ---------------------------------------------------------------------------
// agg_pass: 64 lanes (one wave) per node; each 32-lane half processes edge
// PAIRS (unroll-2) -> 4 KV gathers in flight per iteration. Rank-1 edge-attr
// decomposition as before; halves combined via shfl_xor(.,32).
// ---------------------------------------------------------------------------
__global__ __launch_bounds__(256) void agg_pass(
    const int* __restrict__ cnt, const int2* __restrict__ einfo,
    const float* __restrict__ We, const float* __restrict__ be,
    const unsigned short* __restrict__ Qb, const unsigned short* __restrict__ KVb,
    float* __restrict__ G)
{
    const int tid = threadIdx.x;
    const int node = blockIdx.x * 4 + (tid >> 6);
    if (node >= NNODES) return;
    const int l = tid & 31;          // 4 dims per lane; head = l>>3
    const int h = (tid >> 5) & 1;    // which 32-lane half of the wave

    const float4 We4 = *(const float4*)(We + l * 4);
    const float4 be4 = *(const float4*)(be + l * 4);

    const ushort4 qu = *(const ushort4*)(Qb + (size_t)node * 128 + l * 4);
    const float q0 = bf2f(qu.x), q1 = bf2f(qu.y), q2 = bf2f(qu.z), q3 = bf2f(qu.w);

    float pwe = q0 * We4.x + q1 * We4.y + q2 * We4.z + q3 * We4.w;
    float pbe = q0 * be4.x + q1 * be4.y + q2 * be4.z + q3 * be4.w;
    pwe += __shfl_xor(pwe, 1); pbe += __shfl_xor(pbe, 1);
    pwe += __shfl_xor(pwe, 2); pbe += __shfl_xor(pbe, 2);
    pwe += __shfl_xor(pwe, 4); pbe += __shfl_xor(pbe, 4);
    const float qWeS = pwe * RSQRT_D;
    const float qbeS = pbe * RSQRT_D;

    float a0 = 0.f, a1 = 0.f, a2 = 0.f, a3 = 0.f;
    float sp = 0.f, spw = 0.f;

    const int deg = min(cnt[node], CAP);
    const int2* ep = einfo + (size_t)node * CAP;

    // half h owns edge pairs {2h, 2h+1}, {4+2h, 4+2h+1}, ...
    for (int jj = 2 * h; jj < deg; jj += 4) {
        const bool has1 = (jj + 1 < deg);
        const int2 e0 = ep[jj];
        const int2 e1 = ep[has1 ? jj + 1 : jj];
        const ushort4 ku0 = *(const ushort4*)(KVb + (size_t)e0.x * 256 + l * 4);
        const ushort4 vu0 = *(const ushort4*)(KVb + (size_t)e0.x * 256 + 128 + l * 4);
        const ushort4 ku1 = *(const ushort4*)(KVb + (size_t)e1.x * 256 + l * 4);
        const ushort4 vu1 = *(const ushort4*)(KVb + (size_t)e1.x * 256 + 128 + l * 4);

        float d0 = q0 * bf2f(ku0.x) + q1 * bf2f(ku0.y)
                 + q2 * bf2f(ku0.z) + q3 * bf2f(ku0.w);
        float d1 = q0 * bf2f(ku1.x) + q1 * bf2f(ku1.y)
                 + q2 * bf2f(ku1.z) + q3 * bf2f(ku1.w);
        d0 += __shfl_xor(d0, 1); d1 += __shfl_xor(d1, 1);
        d0 += __shfl_xor(d0, 2); d1 += __shfl_xor(d1, 2);
        d0 += __shfl_xor(d0, 4); d1 += __shfl_xor(d1, 4);

        const float w0 = __int_as_float(e0.y);
        const float p0 = __expf(d0 * RSQRT_D + w0 * qWeS + qbeS);
        sp += p0; spw += p0 * w0;
        a0 += p0 * bf2f(vu0.x); a1 += p0 * bf2f(vu0.y);
        a2 += p0 * bf2f(vu0.z); a3 += p0 * bf2f(vu0.w);

        if (has1) {
            const float w1 = __int_as_float(e1.y);
            const float p1 = __expf(d1 * RSQRT_D + w1 * qWeS + qbeS);
            sp += p1; spw += p1 * w1;
            a0 += p1 * bf2f(vu1.x); a1 += p1 * bf2f(vu1.y);
            a2 += p1 * bf2f(vu1.z); a3 += p1 * bf2f(vu1.w);
        }
    }

    // combine the two halves
    sp += __shfl_xor(sp, 32); spw += __shfl_xor(spw, 32);
    a0 += __shfl_xor(a0, 32); a1 += __shfl_xor(a1, 32);
    a2 += __shfl_xor(a2, 32); a3 += __shfl_xor(a3, 32);

    const float inv = 1.f / (sp + 1e-16f);
    a0 = (a0 + spw * We4.x + sp * be4.x) * inv;
    a1 = (a1 + spw * We4.y + sp * be4.y) * inv;
    a2 = (a2 + spw * We4.z + sp * be4.z) * inv;
    a3 = (a3 + spw * We4.w + sp * be4.w) * inv;

    // head mean within each 32-half
    a0 += __shfl_xor(a0, 8);  a1 += __shfl_xor(a1, 8);
    a2 += __shfl_xor(a2, 8);  a3 += __shfl_xor(a3, 8);
    a0 += __shfl_xor(a0, 16); a1 += __shfl_xor(a1, 16);
    a2 += __shfl_xor(a2, 16); a3 += __shfl_xor(a3, 16);

    if (h == 0 && l < 8) {
        float4 g;
        g.x = a0 * 0.25f; g.y = a1 * 0.25f; g.z = a2 * 0.25f; g.w = a3 * 0.25f;
        *(float4*)(G + (size_t)node * 32 + l * 4) = g;
    }
}

// ---------------------------------------------------------------------------
// node_pass: y = tanh(G + S); z = tanh(y @ Wmlp + bmlp);
// out = x*z[:,:128] + z[:,128:]
// ---------------------------------------------------------------------------
__global__ __launch_bounds__(256) void node_pass(
    const float* __restrict__ x,
    const float* __restrict__ G, const float* __restrict__ S,
    const float* __restrict__ Wmlp, const float* __restrict__ bmlp,
    float* __restrict__ out)
{
    __shared__ float Wm[32 * 256];
    __shared__ float bm[256];
    __shared__ float yl[64 * 32];

    const int tid = threadIdx.x;
    for (int i = tid; i < 2048; i += 256)
        *(float4*)&Wm[i * 4] = *(const float4*)(Wmlp + i * 4);
    if (tid < 64)
        *(float4*)&bm[tid * 4] = *(const float4*)(bmlp + tid * 4);

    const int n0 = blockIdx.x * 64;

    for (int idx = tid; idx < 64 * 32; idx += 256) {
        const int nl = idx >> 5, d = idx & 31;
        const int n = n0 + nl;
        float yv = 0.f;
        if (n < NNODES)
            yv = tanhf(G[(size_t)n * 32 + d] + S[(size_t)n * 32 + d]);
        yl[idx] = yv;
    }
    __syncthreads();

    for (int idx = tid; idx < 64 * 128; idx += 256) {
        const int nl = idx >> 7, c = idx & 127;
        const int n = n0 + nl;
        if (n >= NNODES) continue;
        float s1 = bm[c], s2 = bm[c + 128];
        const float* yrow = &yl[nl * 32];
        #pragma unroll
        for (int d = 0; d < 32; ++d) {
            const float yv = yrow[d];
            s1 += yv * Wm[d * 256 + c];
            s2 += yv * Wm[d * 256 + c + 128];
        }
        out[(size_t)n * 128 + c] = x[(size_t)n * 128 + c] * tanhf(s1) + tanhf(s2);
    }
}

// ---------------------------------------------------------------------------
extern "C" void kernel_launch(void* const* d_in, const int* in_sizes, int n_in,
                              void* d_out, int out_size, void* d_ws, size_t ws_size,
                              hipStream_t stream) {
    const float* x     = (const float*)d_in[0];
    const float* t     = (const float*)d_in[1];
    const int*   ei    = (const int*)  d_in[2];
    const float* ew    = (const float*)d_in[3];
    const float* Wq    = (const float*)d_in[4];
    const float* bq    = (const float*)d_in[5];
    const float* Wk    = (const float*)d_in[6];
    const float* bk    = (const float*)d_in[7];
    const float* Wv    = (const float*)d_in[8];
    const float* bv    = (const float*)d_in[9];
    const float* We    = (const float*)d_in[10];
    const float* be    = (const float*)d_in[11];
    const float* Wskip = (const float*)d_in[12];
    const float* bskip = (const float*)d_in[13];
    const float* Wmlp  = (const float*)d_in[14];
    const float* bmlp  = (const float*)d_in[15];

    char* p = (char*)d_ws;
    unsigned short* Qb  = (unsigned short*)p; p += (size_t)NNODES * 128 * 2;
    unsigned short* KVb = (unsigned short*)p; p += (size_t)NNODES * 256 * 2;
    float* S       = (float*)p; p += (size_t)NNODES * 32 * 4;
    float* G       = (float*)p; p += (size_t)NNODES * 32 * 4;
    unsigned short* Wt = (unsigned short*)p; p += 416 * 256 * 2;
    float* biascat = (float*)p; p += 416 * 4;
    int2* einfo    = (int2*)p;  p += (size_t)NNODES * CAP * 8;
    int* cnt       = (int*)p;   p += NNODES * 4;

    hipMemsetAsync(cnt, 0, (size_t)NNODES * sizeof(int), stream);

    prep_w<<<416, 256, 0, stream>>>(Wq, bq, Wk, bk, Wv, bv, Wskip, bskip,
                                    Wt, biascat);

    scatter_fill<<<NEDGES / 256, 256, 0, stream>>>(ei, ew, cnt, einfo);

    dim3 gg((NNODES + 127) / 128, 4);
    gemm_mfma<<<gg, 256, 0, stream>>>(x, t, Wt, biascat, Qb, KVb, S);

    agg_pass<<<(NNODES + 3) / 4, 256, 0, stream>>>(cnt, einfo, We, be, Qb, KVb, G);

    node_pass<<<(NNODES + 63) / 64, 256, 0, stream>>>(x, G, S, Wmlp, bmlp,
                                                      (float*)d_out);
}

// Round 8
// 387.692 us; speedup vs baseline: 1.0042x; 1.0037x over previous
//
#include <hip/hip_runtime.h>
#include <hip/hip_bf16.h>

#define NNODES 50000
#define NEDGES 800000
#define CAP 64                       // padded-CSR capacity (max degree ~45, Poisson(16))
#define RSQRT_D 0.17677669529663687f // 1/sqrt(32)

typedef short short8 __attribute__((ext_vector_type(8)));   // 8 bf16 (4 VGPRs)
typedef float f32x4 __attribute__((ext_vector_type(4)));    // MFMA accumulator

__device__ inline unsigned short f2bf(float f) {
    union { float f; unsigned u; } v; v.f = f;
    unsigned r = (v.u + 0x7fff + ((v.u >> 16) & 1)) >> 16;   // round-to-nearest-even
    return (unsigned short)r;
}
__device__ inline float bf2f(unsigned short u) {
    union { unsigned u; float f; } v; v.u = ((unsigned)u) << 16;
    return v.f;
}

// ---------------------------------------------------------------------------
// prep_w: Wt[col][k] bf16 (col 0..415 = Q|K|V|skip), biascat[col] fp32.
// ---------------------------------------------------------------------------
__global__ __launch_bounds__(256) void prep_w(
    const float* __restrict__ Wq, const float* __restrict__ bq,
    const float* __restrict__ Wk, const float* __restrict__ bk,
    const float* __restrict__ Wv, const float* __restrict__ bv,
    const float* __restrict__ Wskip, const float* __restrict__ bskip,
    unsigned short* __restrict__ Wt, float* __restrict__ biascat)
{
    const int col = blockIdx.x;
    const int k = threadIdx.x;
    float v; float b;
    if (col < 128)      { v = Wq[k * 128 + col];          b = bq[col]; }
    else if (col < 256) { v = Wk[k * 128 + col - 128];    b = bk[col - 128]; }
    else if (col < 384) { v = Wv[k * 128 + col - 256];    b = bv[col - 256]; }
    else                { v = Wskip[k * 32 + col - 384];  b = bskip[col - 384]; }
    Wt[col * 256 + k] = f2bf(v);
    if (k == 0) biascat[col] = b;
}

// ---------------------------------------------------------------------------
// gemm_mfma: C = y0 @ Wt^T + bias, SINGLE-bf16 A (R7 lesson: split hi/lo A
// needed 128 VGPR for fragments alone -> VGPR_Count hit 128 cap and spilled
// to scratch: WRITE_SIZE 110 MB vs 45 expected, 70k cyc/wave). Single-bf16:
// A-frags 32 VGPR + ping-pong B 64 VGPR ~= 120 total -> no spill, 4 w/SIMD.
// 16 rows/wave; grid.y=4 splits 26 col-tiles 7/7/6/6 (12512-wave supply).
// ---------------------------------------------------------------------------
#define LOADB(buf, ct) do {                                                    \
    const int c_ = (ct) * 16 + row16;                                          \
    _Pragma("unroll")                                                          \
    for (int kt_ = 0; kt_ < 8; ++kt_)                                          \
        buf[kt_] = *(const short8*)(Wt + (size_t)c_ * 256 + kt_ * 32 + quad * 8); \
} while (0)

#define DOTILE(buf, ct) do {                                                   \
    const int c_ = (ct) * 16 + row16;                                          \
    f32x4 acc = {0.f, 0.f, 0.f, 0.f};                                          \
    _Pragma("unroll")                                                          \
    for (int kt_ = 0; kt_ < 8; ++kt_)                                          \
        acc = __builtin_amdgcn_mfma_f32_16x16x32_bf16(a[kt_], buf[kt_], acc, 0, 0, 0); \
    const float bias_ = biascat[c_];                                           \
    _Pragma("unroll")                                                          \
    for (int i_ = 0; i_ < 4; ++i_) {                                           \
        const int m_ = n0 + quad * 4 + i_;                                     \
        if (m_ < NNODES) {                                                     \
            const float val_ = acc[i_] + bias_;                                \
            if (c_ < 128)      Qb[(size_t)m_ * 128 + c_] = f2bf(val_);         \
            else if (c_ < 256) KVb[(size_t)m_ * 256 + (c_ - 128)] = f2bf(val_);\
            else if (c_ < 384) KVb[(size_t)m_ * 256 + 128 + (c_ - 256)] = f2bf(val_); \
            else               S[(size_t)m_ * 32 + (c_ - 384)] = val_;         \
        }                                                                      \
    }                                                                          \
} while (0)

__global__ __launch_bounds__(256, 3) void gemm_mfma(
    const float* __restrict__ x, const float* __restrict__ t,
    const unsigned short* __restrict__ Wt, const float* __restrict__ biascat,
    unsigned short* __restrict__ Qb, unsigned short* __restrict__ KVb,
    float* __restrict__ S)
{
    const int tid = threadIdx.x;
    const int wave = tid >> 6;
    const int lane = tid & 63;
    const int row16 = lane & 15;
    const int quad = lane >> 4;

    const int n0 = blockIdx.x * 64 + wave * 16;    // 16 rows per wave
    const int row = n0 + row16;
    const int by = blockIdx.y;                     // 0..3
    const int ct0 = by * 7 - ((by >= 2) ? (by - 2) : 0);   // 0,7,14,20
    const int nct = (by < 2) ? 7 : 6;
    const int ctEnd = ct0 + nct;

    short8 a[8];
    const float tv = (row < NNODES) ? t[row] : 0.f;

    #pragma unroll
    for (int kt = 0; kt < 8; ++kt) {
        const int kk = kt * 32 + quad * 8;
        const int kx = (kk < 128) ? kk : (kk - 128);
        float4 f0 = make_float4(0, 0, 0, 0), f1 = f0;
        if (row < NNODES) {
            const float* xr = x + (size_t)row * 128 + kx;
            f0 = *(const float4*)xr;
            f1 = *(const float4*)(xr + 4);
            if (kk >= 128) {
                f0.x *= tv; f0.y *= tv; f0.z *= tv; f0.w *= tv;
                f1.x *= tv; f1.y *= tv; f1.z *= tv; f1.w *= tv;
            }
        }
        float fv[8] = { f0.x, f0.y, f0.z, f0.w, f1.x, f1.y, f1.z, f1.w };
        short8 frag;
        #pragma unroll
        for (int j = 0; j < 8; ++j) frag[j] = (short)f2bf(fv[j]);
        a[kt] = frag;
    }

    short8 b0[8], b1[8];
    LOADB(b0, ct0);
    for (int ct = ct0; ct < ctEnd; ct += 2) {
        if (ct + 1 < ctEnd) LOADB(b1, ct + 1);
        DOTILE(b0, ct);
        if (ct + 1 < ctEnd) {
            if (ct + 2 < ctEnd) LOADB(b0, ct + 2);
            DOTILE(b1, ct + 1);
        }
    }
}

// ---------------------------------------------------------------------------
// scatter_fill: padded CSR in ONE pass — no histogram, no prefix scan.
// ---------------------------------------------------------------------------
__global__ __launch_bounds__(256) void scatter_fill(
    const int* __restrict__ ei, const float* __restrict__ ew,
    int* __restrict__ cnt, int2* __restrict__ einfo)
{
    const int e = blockIdx.x * 256 + threadIdx.x;
    if (e >= NEDGES) return;
    const int src = ei[e];
    const int dst = ei[NEDGES + e];
    const int pos = atomicAdd(&cnt[dst], 1);
    if (pos < CAP) {
        int2 v; v.x = src; v.y = __float_as_int(ew[e]);
        einfo[(size_t)dst * CAP + pos] = v;
    }
}

// ---------------------------------------------------------------------------
// agg_pass: 64 lanes (one wave) per node; each 32-lane half processes edge
// PAIRS (unroll-2) -> 4 KV gathers in flight per iteration. Rank-1 edge-attr
// decomposition; halves combined via shfl_xor(.,32).
// ---------------------------------------------------------------------------
__global__ __launch_bounds__(256) void agg_pass(
    const int* __restrict__ cnt, const int2* __restrict__ einfo,
    const float* __restrict__ We, const float* __restrict__ be,
    const unsigned short* __restrict__ Qb, const unsigned short* __restrict__ KVb,
    float* __restrict__ G)
{
    const int tid = threadIdx.x;
    const int node = blockIdx.x * 4 + (tid >> 6);
    if (node >= NNODES) return;
    const int l = tid & 31;          // 4 dims per lane; head = l>>3
    const int h = (tid >> 5) & 1;    // which 32-lane half of the wave

    const float4 We4 = *(const float4*)(We + l * 4);
    const float4 be4 = *(const float4*)(be + l * 4);

    const ushort4 qu = *(const ushort4*)(Qb + (size_t)node * 128 + l * 4);
    const float q0 = bf2f(qu.x), q1 = bf2f(qu.y), q2 = bf2f(qu.z), q3 = bf2f(qu.w);

    float pwe = q0 * We4.x + q1 * We4.y + q2 * We4.z + q3 * We4.w;
    float pbe = q0 * be4.x + q1 * be4.y + q2 * be4.z + q3 * be4.w;
    pwe += __shfl_xor(pwe, 1); pbe += __shfl_xor(pbe, 1);
    pwe += __shfl_xor(pwe, 2); pbe += __shfl_xor(pbe, 2);
    pwe += __shfl_xor(pwe, 4); pbe += __shfl_xor(pbe, 4);
    const float qWeS = pwe * RSQRT_D;
    const float qbeS = pbe * RSQRT_D;

    float a0 = 0.f, a1 = 0.f, a2 = 0.f, a3 = 0.f;
    float sp = 0.f, spw = 0.f;

    const int deg = min(cnt[node], CAP);
    const int2* ep = einfo + (size_t)node * CAP;

    for (int jj = 2 * h; jj < deg; jj += 4) {
        const bool has1 = (jj + 1 < deg);
        const int2 e0 = ep[jj];
        const int2 e1 = ep[has1 ? jj + 1 : jj];
        const ushort4 ku0 = *(const ushort4*)(KVb + (size_t)e0.x * 256 + l * 4);
        const ushort4 vu0 = *(const ushort4*)(KVb + (size_t)e0.x * 256 + 128 + l * 4);
        const ushort4 ku1 = *(const ushort4*)(KVb + (size_t)e1.x * 256 + l * 4);
        const ushort4 vu1 = *(const ushort4*)(KVb + (size_t)e1.x * 256 + 128 + l * 4);

        float d0 = q0 * bf2f(ku0.x) + q1 * bf2f(ku0.y)
                 + q2 * bf2f(ku0.z) + q3 * bf2f(ku0.w);
        float d1 = q0 * bf2f(ku1.x) + q1 * bf2f(ku1.y)
                 + q2 * bf2f(ku1.z) + q3 * bf2f(ku1.w);
        d0 += __shfl_xor(d0, 1); d1 += __shfl_xor(d1, 1);
        d0 += __shfl_xor(d0, 2); d1 += __shfl_xor(d1, 2);
        d0 += __shfl_xor(d0, 4); d1 += __shfl_xor(d1, 4);

        const float w0 = __int_as_float(e0.y);
        const float p0 = __expf(d0 * RSQRT_D + w0 * qWeS + qbeS);
        sp += p0; spw += p0 * w0;
        a0 += p0 * bf2f(vu0.x); a1 += p0 * bf2f(vu0.y);
        a2 += p0 * bf2f(vu0.z); a3 += p0 * bf2f(vu0.w);

        if (has1) {
            const float w1 = __int_as_float(e1.y);
            const float p1 = __expf(d1 * RSQRT_D + w1 * qWeS + qbeS);
            sp += p1; spw += p1 * w1;
            a0 += p1 * bf2f(vu1.x); a1 += p1 * bf2f(vu1.y);
            a2 += p1 * bf2f(vu1.z); a3 += p1 * bf2f(vu1.w);
        }
    }

    sp += __shfl_xor(sp, 32); spw += __shfl_xor(spw, 32);
    a0 += __shfl_xor(a0, 32); a1 += __shfl_xor(a1, 32);
    a2 += __shfl_xor(a2, 32); a3 += __shfl_xor(a3, 32);

    const float inv = 1.f / (sp + 1e-16f);
    a0 = (a0 + spw * We4.x + sp * be4.x) * inv;
    a1 = (a1 + spw * We4.y + sp * be4.y) * inv;
    a2 = (a2 + spw * We4.z + sp * be4.z) * inv;
    a3 = (a3 + spw * We4.w + sp * be4.w) * inv;

    a0 += __shfl_xor(a0, 8);  a1 += __shfl_xor(a1, 8);
    a2 += __shfl_xor(a2, 8);  a3 += __shfl_xor(a3, 8);
    a0 += __shfl_xor(a0, 16); a1 += __shfl_xor(a1, 16);
    a2 += __shfl_xor(a2, 16); a3 += __shfl_xor(a3, 16);

    if (h == 0 && l < 8) {
        float4 g;
        g.x = a0 * 0.25f; g.y = a1 * 0.25f; g.z = a2 * 0.25f; g.w = a3 * 0.25f;
        *(float4*)(G + (size_t)node * 32 + l * 4) = g;
    }
}

// ---------------------------------------------------------------------------
// node_pass: y = tanh(G + S); z = tanh(y @ Wmlp + bmlp);
// out = x*z[:,:128] + z[:,128:]
// ---------------------------------------------------------------------------
__global__ __launch_bounds__(256) void node_pass(
    const float* __restrict__ x,
    const float* __restrict__ G, const float* __restrict__ S,
    const float* __restrict__ Wmlp, const float* __restrict__ bmlp,
    float* __restrict__ out)
{
    __shared__ float Wm[32 * 256];
    __shared__ float bm[256];
    __shared__ float yl[64 * 32];

    const int tid = threadIdx.x;
    for (int i = tid; i < 2048; i += 256)
        *(float4*)&Wm[i * 4] = *(const float4*)(Wmlp + i * 4);
    if (tid < 64)
        *(float4*)&bm[tid * 4] = *(const float4*)(bmlp + tid * 4);

    const int n0 = blockIdx.x * 64;

    for (int idx = tid; idx < 64 * 32; idx += 256) {
        const int nl = idx >> 5, d = idx & 31;
        const int n = n0 + nl;
        float yv = 0.f;
        if (n < NNODES)
            yv = tanhf(G[(size_t)n * 32 + d] + S[(size_t)n * 32 + d]);
        yl[idx] = yv;
    }
    __syncthreads();

    for (int idx = tid; idx < 64 * 128; idx += 256) {
        const int nl = idx >> 7, c = idx & 127;
        const int n = n0 + nl;
        if (n >= NNODES) continue;
        float s1 = bm[c], s2 = bm[c + 128];
        const float* yrow = &yl[nl * 32];
        #pragma unroll
        for (int d = 0; d < 32; ++d) {
            const float yv = yrow[d];
            s1 += yv * Wm[d * 256 + c];
            s2 += yv * Wm[d * 256 + c + 128];
        }
        out[(size_t)n * 128 + c] = x[(size_t)n * 128 + c] * tanhf(s1) + tanhf(s2);
    }
}

// ---------------------------------------------------------------------------
extern "C" void kernel_launch(void* const* d_in, const int* in_sizes, int n_in,
                              void* d_out, int out_size, void* d_ws, size_t ws_size,
                              hipStream_t stream) {
    const float* x     = (const float*)d_in[0];
    const float* t     = (const float*)d_in[1];
    const int*   ei    = (const int*)  d_in[2];
    const float* ew    = (const float*)d_in[3];
    const float* Wq    = (const float*)d_in[4];
    const float* bq    = (const float*)d_in[5];
    const float* Wk    = (const float*)d_in[6];
    const float* bk    = (const float*)d_in[7];
    const float* Wv    = (const float*)d_in[8];
    const float* bv    = (const float*)d_in[9];
    const float* We    = (const float*)d_in[10];
    const float* be    = (const float*)d_in[11];
    const float* Wskip = (const float*)d_in[12];
    const float* bskip = (const float*)d_in[13];
    const float* Wmlp  = (const float*)d_in[14];
    const float* bmlp  = (const float*)d_in[15];

    char* p = (char*)d_ws;
    unsigned short* Qb  = (unsigned short*)p; p += (size_t)NNODES * 128 * 2;
    unsigned short* KVb = (unsigned short*)p; p += (size_t)NNODES * 256 * 2;
    float* S       = (float*)p; p += (size_t)NNODES * 32 * 4;
    float* G       = (float*)p; p += (size_t)NNODES * 32 * 4;
    unsigned short* Wt = (unsigned short*)p; p += 416 * 256 * 2;
    float* biascat = (float*)p; p += 416 * 4;
    int2* einfo    = (int2*)p;  p += (size_t)NNODES * CAP * 8;
    int* cnt       = (int*)p;   p += NNODES * 4;

    hipMemsetAsync(cnt, 0, (size_t)NNODES * sizeof(int), stream);

    prep_w<<<416, 256, 0, stream>>>(Wq, bq, Wk, bk, Wv, bv, Wskip, bskip,
                                    Wt, biascat);

    scatter_fill<<<NEDGES / 256, 256, 0, stream>>>(ei, ew, cnt, einfo);

    dim3 gg((NNODES + 63) / 64, 4);
    gemm_mfma<<<gg, 256, 0, stream>>>(x, t, Wt, biascat, Qb, KVb, S);

    agg_pass<<<(NNODES + 3) / 4, 256, 0, stream>>>(cnt, einfo, We, be, Qb, KVb, G);

    node_pass<<<(NNODES + 63) / 64, 256, 0, stream>>>(x, G, S, Wmlp, bmlp,
                                                      (float*)d_out);
}

// Round 9
// 355.140 us; speedup vs baseline: 1.0963x; 1.0917x over previous
//
#include <hip/hip_runtime.h>
#include <hip/hip_bf16.h>

#define NNODES 50000
#define NEDGES 800000
#define CAP 64                       // padded-CSR capacity (max degree ~45, Poisson(16))
#define RSQRT_D 0.17677669529663687f // 1/sqrt(32)

typedef short short8 __attribute__((ext_vector_type(8)));   // 8 bf16 (4 VGPRs)
typedef float f32x4 __attribute__((ext_vector_type(4)));    // MFMA accumulator

__device__ inline unsigned short f2bf(float f) {
    union { float f; unsigned u; } v; v.f = f;
    unsigned r = (v.u + 0x7fff + ((v.u >> 16) & 1)) >> 16;   // round-to-nearest-even
    return (unsigned short)r;
}
__device__ inline float bf2f(unsigned short u) {
    union { unsigned u; float f; } v; v.u = ((unsigned)u) << 16;
    return v.f;
}

// ---------------------------------------------------------------------------
// prep_w: Wt[col][k] bf16 (col 0..415 = Q|K|V|skip), biascat[col] fp32.
// ---------------------------------------------------------------------------
__global__ __launch_bounds__(256) void prep_w(
    const float* __restrict__ Wq, const float* __restrict__ bq,
    const float* __restrict__ Wk, const float* __restrict__ bk,
    const float* __restrict__ Wv, const float* __restrict__ bv,
    const float* __restrict__ Wskip, const float* __restrict__ bskip,
    unsigned short* __restrict__ Wt, float* __restrict__ biascat)
{
    const int col = blockIdx.x;
    const int k = threadIdx.x;
    float v; float b;
    if (col < 128)      { v = Wq[k * 128 + col];          b = bq[col]; }
    else if (col < 256) { v = Wk[k * 128 + col - 128];    b = bk[col - 128]; }
    else if (col < 384) { v = Wv[k * 128 + col - 256];    b = bv[col - 256]; }
    else                { v = Wskip[k * 32 + col - 384];  b = bskip[col - 384]; }
    Wt[col * 256 + k] = f2bf(v);
    if (k == 0) biascat[col] = b;
}

// ---------------------------------------------------------------------------
// gemm_mfma: C = y0 @ Wt^T + bias, single-bf16 A, MFMA 16x16x32.
// R8 lesson: reading B-frags straight from global made every short8 load a
// 16-segment gather (~900 L2 transactions/wave) — VMEM-request bound at
// ~120 us regardless of occupancy/ILP. Fix: stage the block's Wt slice in
// LDS ONCE with coalesced 16B loads; K-loop is then ds_read_b128 + MFMA.
// LDS cols padded to 264 shorts -> bank-uniform b128 reads (8/bank).
// 16 rows/wave; grid.y=4 splits 26 col-tiles 7/7/6/6; 59KB LDS, 2 blocks/CU.
// ---------------------------------------------------------------------------
__global__ __launch_bounds__(256) void gemm_mfma(
    const float* __restrict__ x, const float* __restrict__ t,
    const unsigned short* __restrict__ Wt, const float* __restrict__ biascat,
    unsigned short* __restrict__ Qb, unsigned short* __restrict__ KVb,
    float* __restrict__ S)
{
    __shared__ unsigned short Bs[7 * 16 * 264];    // [col][k], k padded 256->264

    const int tid = threadIdx.x;
    const int wave = tid >> 6;
    const int lane = tid & 63;
    const int row16 = lane & 15;
    const int quad = lane >> 4;

    const int n0 = blockIdx.x * 64 + wave * 16;    // 16 rows per wave
    const int row = n0 + row16;
    const int by = blockIdx.y;                     // 0..3
    const int ct0 = by * 7 - ((by >= 2) ? (by - 2) : 0);   // 0,7,14,20
    const int nct = (by < 2) ? 7 : 6;
    const int ncols = nct * 16;                    // 112 or 96

    // ---- A fragments (registers, unchanged from R8) ----
    short8 a[8];
    const float tv = (row < NNODES) ? t[row] : 0.f;
    #pragma unroll
    for (int kt = 0; kt < 8; ++kt) {
        const int kk = kt * 32 + quad * 8;
        const int kx = (kk < 128) ? kk : (kk - 128);
        float4 f0 = make_float4(0, 0, 0, 0), f1 = f0;
        if (row < NNODES) {
            const float* xr = x + (size_t)row * 128 + kx;
            f0 = *(const float4*)xr;
            f1 = *(const float4*)(xr + 4);
            if (kk >= 128) {
                f0.x *= tv; f0.y *= tv; f0.z *= tv; f0.w *= tv;
                f1.x *= tv; f1.y *= tv; f1.z *= tv; f1.w *= tv;
            }
        }
        float fv[8] = { f0.x, f0.y, f0.z, f0.w, f1.x, f1.y, f1.z, f1.w };
        short8 frag;
        #pragma unroll
        for (int j = 0; j < 8; ++j) frag[j] = (short)f2bf(fv[j]);
        a[kt] = frag;
    }

    // ---- Stage Wt slice into LDS, coalesced (tid -> consecutive 16B) ----
    for (int idx = tid; idx < ncols * 32; idx += 256) {
        const int c = idx >> 5;              // local col 0..ncols-1
        const int k8 = (idx & 31) * 8;       // 0,8,...,248
        const short8 v = *(const short8*)(Wt + (size_t)(ct0 * 16 + c) * 256 + k8);
        *(short8*)&Bs[c * 264 + k8] = v;
    }
    __syncthreads();

    // ---- K-loop per col-tile: ds_read_b128 + MFMA ----
    for (int tl = 0; tl < nct; ++tl) {
        const int c = (ct0 + tl) * 16 + row16;           // global col
        const unsigned short* bp = &Bs[(tl * 16 + row16) * 264 + quad * 8];
        f32x4 acc = {0.f, 0.f, 0.f, 0.f};
        #pragma unroll
        for (int kt = 0; kt < 8; ++kt) {
            const short8 b = *(const short8*)(bp + kt * 32);
            acc = __builtin_amdgcn_mfma_f32_16x16x32_bf16(a[kt], b, acc, 0, 0, 0);
        }
        const float bias = biascat[c];
        // D: col = row16 (== c), row = quad*4 + i. Wave-uniform branches.
        #pragma unroll
        for (int i = 0; i < 4; ++i) {
            const int m = n0 + quad * 4 + i;
            if (m >= NNODES) continue;
            const float val = acc[i] + bias;
            if (c < 128)      Qb[(size_t)m * 128 + c] = f2bf(val);
            else if (c < 256) KVb[(size_t)m * 256 + (c - 128)] = f2bf(val);
            else if (c < 384) KVb[(size_t)m * 256 + 128 + (c - 256)] = f2bf(val);
            else              S[(size_t)m * 32 + (c - 384)] = val;
        }
    }
}

// ---------------------------------------------------------------------------
// scatter_fill: padded CSR in ONE pass — no histogram, no prefix scan.
// ---------------------------------------------------------------------------
__global__ __launch_bounds__(256) void scatter_fill(
    const int* __restrict__ ei, const float* __restrict__ ew,
    int* __restrict__ cnt, int2* __restrict__ einfo)
{
    const int e = blockIdx.x * 256 + threadIdx.x;
    if (e >= NEDGES) return;
    const int src = ei[e];
    const int dst = ei[NEDGES + e];
    const int pos = atomicAdd(&cnt[dst], 1);
    if (pos < CAP) {
        int2 v; v.x = src; v.y = __float_as_int(ew[e]);
        einfo[(size_t)dst * CAP + pos] = v;
    }
}

// ---------------------------------------------------------------------------
// agg_pass: 64 lanes (one wave) per node; each 32-lane half processes edge
// PAIRS (unroll-2) -> 4 KV gathers in flight per iteration. Rank-1 edge-attr
// decomposition; halves combined via shfl_xor(.,32).
// ---------------------------------------------------------------------------
__global__ __launch_bounds__(256) void agg_pass(
    const int* __restrict__ cnt, const int2* __restrict__ einfo,
    const float* __restrict__ We, const float* __restrict__ be,
    const unsigned short* __restrict__ Qb, const unsigned short* __restrict__ KVb,
    float* __restrict__ G)
{
    const int tid = threadIdx.x;
    const int node = blockIdx.x * 4 + (tid >> 6);
    if (node >= NNODES) return;
    const int l = tid & 31;          // 4 dims per lane; head = l>>3
    const int h = (tid >> 5) & 1;    // which 32-lane half of the wave

    const float4 We4 = *(const float4*)(We + l * 4);
    const float4 be4 = *(const float4*)(be + l * 4);

    const ushort4 qu = *(const ushort4*)(Qb + (size_t)node * 128 + l * 4);
    const float q0 = bf2f(qu.x), q1 = bf2f(qu.y), q2 = bf2f(qu.z), q3 = bf2f(qu.w);

    float pwe = q0 * We4.x + q1 * We4.y + q2 * We4.z + q3 * We4.w;
    float pbe = q0 * be4.x + q1 * be4.y + q2 * be4.z + q3 * be4.w;
    pwe += __shfl_xor(pwe, 1); pbe += __shfl_xor(pbe, 1);
    pwe += __shfl_xor(pwe, 2); pbe += __shfl_xor(pbe, 2);
    pwe += __shfl_xor(pwe, 4); pbe += __shfl_xor(pbe, 4);
    const float qWeS = pwe * RSQRT_D;
    const float qbeS = pbe * RSQRT_D;

    float a0 = 0.f, a1 = 0.f, a2 = 0.f, a3 = 0.f;
    float sp = 0.f, spw = 0.f;

    const int deg = min(cnt[node], CAP);
    const int2* ep = einfo + (size_t)node * CAP;

    for (int jj = 2 * h; jj < deg; jj += 4) {
        const bool has1 = (jj + 1 < deg);
        const int2 e0 = ep[jj];
        const int2 e1 = ep[has1 ? jj + 1 : jj];
        const ushort4 ku0 = *(const ushort4*)(KVb + (size_t)e0.x * 256 + l * 4);
        const ushort4 vu0 = *(const ushort4*)(KVb + (size_t)e0.x * 256 + 128 + l * 4);
        const ushort4 ku1 = *(const ushort4*)(KVb + (size_t)e1.x * 256 + l * 4);
        const ushort4 vu1 = *(const ushort4*)(KVb + (size_t)e1.x * 256 + 128 + l * 4);

        float d0 = q0 * bf2f(ku0.x) + q1 * bf2f(ku0.y)
                 + q2 * bf2f(ku0.z) + q3 * bf2f(ku0.w);
        float d1 = q0 * bf2f(ku1.x) + q1 * bf2f(ku1.y)
                 + q2 * bf2f(ku1.z) + q3 * bf2f(ku1.w);
        d0 += __shfl_xor(d0, 1); d1 += __shfl_xor(d1, 1);
        d0 += __shfl_xor(d0, 2); d1 += __shfl_xor(d1, 2);
        d0 += __shfl_xor(d0, 4); d1 += __shfl_xor(d1, 4);

        const float w0 = __int_as_float(e0.y);
        const float p0 = __expf(d0 * RSQRT_D + w0 * qWeS + qbeS);
        sp += p0; spw += p0 * w0;
        a0 += p0 * bf2f(vu0.x); a1 += p0 * bf2f(vu0.y);
        a2 += p0 * bf2f(vu0.z); a3 += p0 * bf2f(vu0.w);

        if (has1) {
            const float w1 = __int_as_float(e1.y);
            const float p1 = __expf(d1 * RSQRT_D + w1 * qWeS + qbeS);
            sp += p1; spw += p1 * w1;
            a0 += p1 * bf2f(vu1.x); a1 += p1 * bf2f(vu1.y);
            a2 += p1 * bf2f(vu1.z); a3 += p1 * bf2f(vu1.w);
        }
    }

    sp += __shfl_xor(sp, 32); spw += __shfl_xor(spw, 32);
    a0 += __shfl_xor(a0, 32); a1 += __shfl_xor(a1, 32);
    a2 += __shfl_xor(a2, 32); a3 += __shfl_xor(a3, 32);

    const float inv = 1.f / (sp + 1e-16f);
    a0 = (a0 + spw * We4.x + sp * be4.x) * inv;
    a1 = (a1 + spw * We4.y + sp * be4.y) * inv;
    a2 = (a2 + spw * We4.z + sp * be4.z) * inv;
    a3 = (a3 + spw * We4.w + sp * be4.w) * inv;

    a0 += __shfl_xor(a0, 8);  a1 += __shfl_xor(a1, 8);
    a2 += __shfl_xor(a2, 8);  a3 += __shfl_xor(a3, 8);
    a0 += __shfl_xor(a0, 16); a1 += __shfl_xor(a1, 16);
    a2 += __shfl_xor(a2, 16); a3 += __shfl_xor(a3, 16);

    if (h == 0 && l < 8) {
        float4 g;
        g.x = a0 * 0.25f; g.y = a1 * 0.25f; g.z = a2 * 0.25f; g.w = a3 * 0.25f;
        *(float4*)(G + (size_t)node * 32 + l * 4) = g;
    }
}

// ---------------------------------------------------------------------------
// node_pass: y = tanh(G + S); z = tanh(y @ Wmlp + bmlp);
// out = x*z[:,:128] + z[:,128:]
// ---------------------------------------------------------------------------
__global__ __launch_bounds__(256) void node_pass(
    const float* __restrict__ x,
    const float* __restrict__ G, const float* __restrict__ S,
    const float* __restrict__ Wmlp, const float* __restrict__ bmlp,
    float* __restrict__ out)
{
    __shared__ float Wm[32 * 256];
    __shared__ float bm[256];
    __shared__ float yl[64 * 32];

    const int tid = threadIdx.x;
    for (int i = tid; i < 2048; i += 256)
        *(float4*)&Wm[i * 4] = *(const float4*)(Wmlp + i * 4);
    if (tid < 64)
        *(float4*)&bm[tid * 4] = *(const float4*)(bmlp + tid * 4);

    const int n0 = blockIdx.x * 64;

    for (int idx = tid; idx < 64 * 32; idx += 256) {
        const int nl = idx >> 5, d = idx & 31;
        const int n = n0 + nl;
        float yv = 0.f;
        if (n < NNODES)
            yv = tanhf(G[(size_t)n * 32 + d] + S[(size_t)n * 32 + d]);
        yl[idx] = yv;
    }
    __syncthreads();

    for (int idx = tid; idx < 64 * 128; idx += 256) {
        const int nl = idx >> 7, c = idx & 127;
        const int n = n0 + nl;
        if (n >= NNODES) continue;
        float s1 = bm[c], s2 = bm[c + 128];
        const float* yrow = &yl[nl * 32];
        #pragma unroll
        for (int d = 0; d < 32; ++d) {
            const float yv = yrow[d];
            s1 += yv * Wm[d * 256 + c];
            s2 += yv * Wm[d * 256 + c + 128];
        }
        out[(size_t)n * 128 + c] = x[(size_t)n * 128 + c] * tanhf(s1) + tanhf(s2);
    }
}

// ---------------------------------------------------------------------------
extern "C" void kernel_launch(void* const* d_in, const int* in_sizes, int n_in,
                              void* d_out, int out_size, void* d_ws, size_t ws_size,
                              hipStream_t stream) {
    const float* x     = (const float*)d_in[0];
    const float* t     = (const float*)d_in[1];
    const int*   ei    = (const int*)  d_in[2];
    const float* ew    = (const float*)d_in[3];
    const float* Wq    = (const float*)d_in[4];
    const float* bq    = (const float*)d_in[5];
    const float* Wk    = (const float*)d_in[6];
    const float* bk    = (const float*)d_in[7];
    const float* Wv    = (const float*)d_in[8];
    const float* bv    = (const float*)d_in[9];
    const float* We    = (const float*)d_in[10];
    const float* be    = (const float*)d_in[11];
    const float* Wskip = (const float*)d_in[12];
    const float* bskip = (const float*)d_in[13];
    const float* Wmlp  = (const float*)d_in[14];
    const float* bmlp  = (const float*)d_in[15];

    char* p = (char*)d_ws;
    unsigned short* Qb  = (unsigned short*)p; p += (size_t)NNODES * 128 * 2;
    unsigned short* KVb = (unsigned short*)p; p += (size_t)NNODES * 256 * 2;
    float* S       = (float*)p; p += (size_t)NNODES * 32 * 4;
    float* G       = (float*)p; p += (size_t)NNODES * 32 * 4;
    unsigned short* Wt = (unsigned short*)p; p += 416 * 256 * 2;
    float* biascat = (float*)p; p += 416 * 4;
    int2* einfo    = (int2*)p;  p += (size_t)NNODES * CAP * 8;
    int* cnt       = (int*)p;   p += NNODES * 4;

    hipMemsetAsync(cnt, 0, (size_t)NNODES * sizeof(int), stream);

    prep_w<<<416, 256, 0, stream>>>(Wq, bq, Wk, bk, Wv, bv, Wskip, bskip,
                                    Wt, biascat);

    scatter_fill<<<NEDGES / 256, 256, 0, stream>>>(ei, ew, cnt, einfo);

    dim3 gg((NNODES + 63) / 64, 4);
    gemm_mfma<<<gg, 256, 0, stream>>>(x, t, Wt, biascat, Qb, KVb, S);

    agg_pass<<<(NNODES + 3) / 4, 256, 0, stream>>>(cnt, einfo, We, be, Qb, KVb, G);

    node_pass<<<(NNODES + 63) / 64, 256, 0, stream>>>(x, G, S, Wmlp, bmlp,
                                                      (float*)d_out);
}

// Round 10
// 327.828 us; speedup vs baseline: 1.1876x; 1.0833x over previous
//
#include <hip/hip_runtime.h>
#include <hip/hip_bf16.h>

#define NNODES 50000
#define NPAD   50048                 // 3128 row-tiles of 16 (covers 391*128)
#define NEDGES 800000
#define CAP 64                       // padded-CSR capacity (max degree ~45, Poisson(16))
#define RSQRT_D 0.17677669529663687f // 1/sqrt(32)

typedef short short8 __attribute__((ext_vector_type(8)));   // 8 bf16 (4 VGPRs)
typedef float f32x4 __attribute__((ext_vector_type(4)));    // MFMA accumulator

__device__ inline unsigned short f2bf(float f) {
    union { float f; unsigned u; } v; v.f = f;
    unsigned r = (v.u + 0x7fff + ((v.u >> 16) & 1)) >> 16;   // round-to-nearest-even
    return (unsigned short)r;
}
__device__ inline float bf2f(unsigned short u) {
    union { unsigned u; float f; } v; v.u = ((unsigned)u) << 16;
    return v.f;
}

// ---------------------------------------------------------------------------
// prep_w: Wtf in MFMA-frag-major layout: chunk (ct*32 + kt*4 + quad) holds
// 16 cols x 8 k-values contiguously -> a wave's A-frag load = 1024 B coalesced.
// col 0..415 = Q|K|V|skip. biascat[col] fp32.
// ---------------------------------------------------------------------------
__global__ __launch_bounds__(256) void prep_w(
    const float* __restrict__ Wq, const float* __restrict__ bq,
    const float* __restrict__ Wk, const float* __restrict__ bk,
    const float* __restrict__ Wv, const float* __restrict__ bv,
    const float* __restrict__ Wskip, const float* __restrict__ bskip,
    unsigned short* __restrict__ Wtf, float* __restrict__ biascat)
{
    const int col = blockIdx.x;
    const int k = threadIdx.x;
    float v; float b;
    if (col < 128)      { v = Wq[k * 128 + col];          b = bq[col]; }
    else if (col < 256) { v = Wk[k * 128 + col - 128];    b = bk[col - 128]; }
    else if (col < 384) { v = Wv[k * 128 + col - 256];    b = bv[col - 256]; }
    else                { v = Wskip[k * 32 + col - 384];  b = bskip[col - 384]; }
    const int ct = col >> 4, c16 = col & 15;
    const int kt = k >> 5, quad = (k >> 3) & 3, j = k & 7;
    Wtf[(size_t)(ct * 32 + kt * 4 + quad) * 128 + c16 * 8 + j] = f2bf(v);
    if (k == 0) biascat[col] = b;
}

// ---------------------------------------------------------------------------
// pack_a: y0 = [x, x*t] -> bf16 in frag-major layout y0f (same chunk scheme,
// rows padded/zeroed to NPAD). Coalesced x reads; 16B scattered writes are
// absorbed by L2 (every byte written -> full-line writeback).
// ---------------------------------------------------------------------------
__global__ __launch_bounds__(256) void pack_a(
    const float* __restrict__ x, const float* __restrict__ t,
    unsigned short* __restrict__ y0f)
{
    const int gid = blockIdx.x * 256 + threadIdx.x;   // NPAD*32 threads exactly
    const int row = gid >> 5;
    const int oct = gid & 31;                          // kt*4+quad
    short8 out = {0, 0, 0, 0, 0, 0, 0, 0};
    if (row < NNODES) {
        const int kb = oct * 8;
        const int kx = (kb < 128) ? kb : (kb - 128);
        const float* xr = x + (size_t)row * 128 + kx;
        float4 f0 = *(const float4*)xr;
        float4 f1 = *(const float4*)(xr + 4);
        if (kb >= 128) {
            const float tv = t[row];
            f0.x *= tv; f0.y *= tv; f0.z *= tv; f0.w *= tv;
            f1.x *= tv; f1.y *= tv; f1.z *= tv; f1.w *= tv;
        }
        out[0] = (short)f2bf(f0.x); out[1] = (short)f2bf(f0.y);
        out[2] = (short)f2bf(f0.z); out[3] = (short)f2bf(f0.w);
        out[4] = (short)f2bf(f1.x); out[5] = (short)f2bf(f1.y);
        out[6] = (short)f2bf(f1.z); out[7] = (short)f2bf(f1.w);
    }
    *(short8*)(y0f + (size_t)((row >> 4) * 32 + oct) * 128 + (row & 15) * 8) = out;
}

// ---------------------------------------------------------------------------
// gemm_mfma: OPERAND-SWAPPED, zero-LDS, zero-barrier, all-coalesced.
// R9 lesson: LDS version still had 16-segment A-gathers + C-scatters and an
// 8-way-conflicted LDS read (my 264-pad bank claim was wrong: 4(c+q) mod 32).
// Now: A-op = Wtf frags (lane16=col), B-op = y0f frags (lane16=node); D row =
// col-in-tile, D col = node -> each lane stores 4 consecutive cols of one node
// (one packed 8B store per tile). Wave = 32 rows x 6-7 col-tiles; ping-pong
// Wt frags; grid 391 x 4 (col-tiles 7/7/6/6).
// ---------------------------------------------------------------------------
#define LOADW(buf, ct) do {                                                    \
    _Pragma("unroll")                                                          \
    for (int kt_ = 0; kt_ < 8; ++kt_)                                          \
        buf[kt_] = *(const short8*)(Wtf + (size_t)((ct) * 32 + kt_ * 4 + quad) * 128 + l16 * 8); \
} while (0)

#define DOTILE(buf, ct) do {                                                   \
    f32x4 acc0 = {0.f, 0.f, 0.f, 0.f}, acc1 = {0.f, 0.f, 0.f, 0.f};            \
    _Pragma("unroll")                                                          \
    for (int kt_ = 0; kt_ < 8; ++kt_) {                                        \
        acc0 = __builtin_amdgcn_mfma_f32_16x16x32_bf16(buf[kt_], b0[kt_], acc0, 0, 0, 0); \
        acc1 = __builtin_amdgcn_mfma_f32_16x16x32_bf16(buf[kt_], b1[kt_], acc1, 0, 0, 0); \
    }                                                                          \
    const int cb_ = (ct) * 16 + quad * 4;                                      \
    const float4 bias_ = *(const float4*)(biascat + cb_);                      \
    _Pragma("unroll")                                                          \
    for (int s_ = 0; s_ < 2; ++s_) {                                           \
        const int m_ = n0 + s_ * 16 + l16;                                     \
        if (m_ < NNODES) {                                                     \
            const f32x4 a_ = s_ ? acc1 : acc0;                                 \
            const float v0_ = a_[0] + bias_.x, v1_ = a_[1] + bias_.y;          \
            const float v2_ = a_[2] + bias_.z, v3_ = a_[3] + bias_.w;          \
            if ((ct) < 24) {                                                   \
                uint2 pk_;                                                     \
                pk_.x = (unsigned)f2bf(v0_) | ((unsigned)f2bf(v1_) << 16);     \
                pk_.y = (unsigned)f2bf(v2_) | ((unsigned)f2bf(v3_) << 16);     \
                if ((ct) < 8)                                                  \
                    *(uint2*)(Qb + (size_t)m_ * 128 + cb_) = pk_;              \
                else                                                           \
                    *(uint2*)(KVb + (size_t)m_ * 256 + (cb_ - 128)) = pk_;     \
            } else {                                                           \
                *(float4*)(S + (size_t)m_ * 32 + (cb_ - 384)) =                \
                    make_float4(v0_, v1_, v2_, v3_);                           \
            }                                                                  \
        }                                                                      \
    }                                                                          \
} while (0)

__global__ __launch_bounds__(256) void gemm_mfma(
    const unsigned short* __restrict__ y0f,
    const unsigned short* __restrict__ Wtf,
    const float* __restrict__ biascat,
    unsigned short* __restrict__ Qb, unsigned short* __restrict__ KVb,
    float* __restrict__ S)
{
    const int tid = threadIdx.x;
    const int wave = tid >> 6;
    const int lane = tid & 63;
    const int l16 = lane & 15;
    const int quad = lane >> 4;

    const int n0 = blockIdx.x * 128 + wave * 32;   // 32 rows per wave
    const int mt0 = n0 >> 4;
    const int by = blockIdx.y;                     // 0..3
    const int ct0 = by * 7 - ((by >= 2) ? (by - 2) : 0);   // 0,7,14,20
    const int nct = (by < 2) ? 7 : 6;
    const int ctEnd = ct0 + nct;

    // y0 B-frags for both 16-row sets: 1024B coalesced per load
    short8 b0[8], b1[8];
    #pragma unroll
    for (int kt = 0; kt < 8; ++kt) {
        b0[kt] = *(const short8*)(y0f + (size_t)((mt0 + 0) * 32 + kt * 4 + quad) * 128 + l16 * 8);
        b1[kt] = *(const short8*)(y0f + (size_t)((mt0 + 1) * 32 + kt * 4 + quad) * 128 + l16 * 8);
    }

    short8 wa[8], wb[8];                           // ping-pong Wt A-frags
    LOADW(wa, ct0);
    for (int ct = ct0; ct < ctEnd; ct += 2) {
        if (ct + 1 < ctEnd) LOADW(wb, ct + 1);
        DOTILE(wa, ct);
        if (ct + 1 < ctEnd) {
            if (ct + 2 < ctEnd) LOADW(wa, ct + 2);
            DOTILE(wb, ct + 1);
        }
    }
}

// ---------------------------------------------------------------------------
// scatter_fill: padded CSR in ONE pass — no histogram, no prefix scan.
// ---------------------------------------------------------------------------
__global__ __launch_bounds__(256) void scatter_fill(
    const int* __restrict__ ei, const float* __restrict__ ew,
    int* __restrict__ cnt, int2* __restrict__ einfo)
{
    const int e = blockIdx.x * 256 + threadIdx.x;
    if (e >= NEDGES) return;
    const int src = ei[e];
    const int dst = ei[NEDGES + e];
    const int pos = atomicAdd(&cnt[dst], 1);
    if (pos < CAP) {
        int2 v; v.x = src; v.y = __float_as_int(ew[e]);
        einfo[(size_t)dst * CAP + pos] = v;
    }
}

// ---------------------------------------------------------------------------
// agg_pass: 64 lanes (one wave) per node; each 32-lane half processes edge
// PAIRS (unroll-2) -> 4 KV gathers in flight per iteration. Rank-1 edge-attr
// decomposition; halves combined via shfl_xor(.,32).
// ---------------------------------------------------------------------------
__global__ __launch_bounds__(256) void agg_pass(
    const int* __restrict__ cnt, const int2* __restrict__ einfo,
    const float* __restrict__ We, const float* __restrict__ be,
    const unsigned short* __restrict__ Qb, const unsigned short* __restrict__ KVb,
    float* __restrict__ G)
{
    const int tid = threadIdx.x;
    const int node = blockIdx.x * 4 + (tid >> 6);
    if (node >= NNODES) return;
    const int l = tid & 31;          // 4 dims per lane; head = l>>3
    const int h = (tid >> 5) & 1;    // which 32-lane half of the wave

    const float4 We4 = *(const float4*)(We + l * 4);
    const float4 be4 = *(const float4*)(be + l * 4);

    const ushort4 qu = *(const ushort4*)(Qb + (size_t)node * 128 + l * 4);
    const float q0 = bf2f(qu.x), q1 = bf2f(qu.y), q2 = bf2f(qu.z), q3 = bf2f(qu.w);

    float pwe = q0 * We4.x + q1 * We4.y + q2 * We4.z + q3 * We4.w;
    float pbe = q0 * be4.x + q1 * be4.y + q2 * be4.z + q3 * be4.w;
    pwe += __shfl_xor(pwe, 1); pbe += __shfl_xor(pbe, 1);
    pwe += __shfl_xor(pwe, 2); pbe += __shfl_xor(pbe, 2);
    pwe += __shfl_xor(pwe, 4); pbe += __shfl_xor(pbe, 4);
    const float qWeS = pwe * RSQRT_D;
    const float qbeS = pbe * RSQRT_D;

    float a0 = 0.f, a1 = 0.f, a2 = 0.f, a3 = 0.f;
    float sp = 0.f, spw = 0.f;

    const int deg = min(cnt[node], CAP);
    const int2* ep = einfo + (size_t)node * CAP;

    for (int jj = 2 * h; jj < deg; jj += 4) {
        const bool has1 = (jj + 1 < deg);
        const int2 e0 = ep[jj];
        const int2 e1 = ep[has1 ? jj + 1 : jj];
        const ushort4 ku0 = *(const ushort4*)(KVb + (size_t)e0.x * 256 + l * 4);
        const ushort4 vu0 = *(const ushort4*)(KVb + (size_t)e0.x * 256 + 128 + l * 4);
        const ushort4 ku1 = *(const ushort4*)(KVb + (size_t)e1.x * 256 + l * 4);
        const ushort4 vu1 = *(const ushort4*)(KVb + (size_t)e1.x * 256 + 128 + l * 4);

        float d0 = q0 * bf2f(ku0.x) + q1 * bf2f(ku0.y)
                 + q2 * bf2f(ku0.z) + q3 * bf2f(ku0.w);
        float d1 = q0 * bf2f(ku1.x) + q1 * bf2f(ku1.y)
                 + q2 * bf2f(ku1.z) + q3 * bf2f(ku1.w);
        d0 += __shfl_xor(d0, 1); d1 += __shfl_xor(d1, 1);
        d0 += __shfl_xor(d0, 2); d1 += __shfl_xor(d1, 2);
        d0 += __shfl_xor(d0, 4); d1 += __shfl_xor(d1, 4);

        const float w0 = __int_as_float(e0.y);
        const float p0 = __expf(d0 * RSQRT_D + w0 * qWeS + qbeS);
        sp += p0; spw += p0 * w0;
        a0 += p0 * bf2f(vu0.x); a1 += p0 * bf2f(vu0.y);
        a2 += p0 * bf2f(vu0.z); a3 += p0 * bf2f(vu0.w);

        if (has1) {
            const float w1 = __int_as_float(e1.y);
            const float p1 = __expf(d1 * RSQRT_D + w1 * qWeS + qbeS);
            sp += p1; spw += p1 * w1;
            a0 += p1 * bf2f(vu1.x); a1 += p1 * bf2f(vu1.y);
            a2 += p1 * bf2f(vu1.z); a3 += p1 * bf2f(vu1.w);
        }
    }

    sp += __shfl_xor(sp, 32); spw += __shfl_xor(spw, 32);
    a0 += __shfl_xor(a0, 32); a1 += __shfl_xor(a1, 32);
    a2 += __shfl_xor(a2, 32); a3 += __shfl_xor(a3, 32);

    const float inv = 1.f / (sp + 1e-16f);
    a0 = (a0 + spw * We4.x + sp * be4.x) * inv;
    a1 = (a1 + spw * We4.y + sp * be4.y) * inv;
    a2 = (a2 + spw * We4.z + sp * be4.z) * inv;
    a3 = (a3 + spw * We4.w + sp * be4.w) * inv;

    a0 += __shfl_xor(a0, 8);  a1 += __shfl_xor(a1, 8);
    a2 += __shfl_xor(a2, 8);  a3 += __shfl_xor(a3, 8);
    a0 += __shfl_xor(a0, 16); a1 += __shfl_xor(a1, 16);
    a2 += __shfl_xor(a2, 16); a3 += __shfl_xor(a3, 16);

    if (h == 0 && l < 8) {
        float4 g;
        g.x = a0 * 0.25f; g.y = a1 * 0.25f; g.z = a2 * 0.25f; g.w = a3 * 0.25f;
        *(float4*)(G + (size_t)node * 32 + l * 4) = g;
    }
}

// ---------------------------------------------------------------------------
// node_pass: y = tanh(G + S); z = tanh(y @ Wmlp + bmlp);
// out = x*z[:,:128] + z[:,128:]
// ---------------------------------------------------------------------------
__global__ __launch_bounds__(256) void node_pass(
    const float* __restrict__ x,
    const float* __restrict__ G, const float* __restrict__ S,
    const float* __restrict__ Wmlp, const float* __restrict__ bmlp,
    float* __restrict__ out)
{
    __shared__ float Wm[32 * 256];
    __shared__ float bm[256];
    __shared__ float yl[64 * 32];

    const int tid = threadIdx.x;
    for (int i = tid; i < 2048; i += 256)
        *(float4*)&Wm[i * 4] = *(const float4*)(Wmlp + i * 4);
    if (tid < 64)
        *(float4*)&bm[tid * 4] = *(const float4*)(bmlp + tid * 4);

    const int n0 = blockIdx.x * 64;

    for (int idx = tid; idx < 64 * 32; idx += 256) {
        const int nl = idx >> 5, d = idx & 31;
        const int n = n0 + nl;
        float yv = 0.f;
        if (n < NNODES)
            yv = tanhf(G[(size_t)n * 32 + d] + S[(size_t)n * 32 + d]);
        yl[idx] = yv;
    }
    __syncthreads();

    for (int idx = tid; idx < 64 * 128; idx += 256) {
        const int nl = idx >> 7, c = idx & 127;
        const int n = n0 + nl;
        if (n >= NNODES) continue;
        float s1 = bm[c], s2 = bm[c + 128];
        const float* yrow = &yl[nl * 32];
        #pragma unroll
        for (int d = 0; d < 32; ++d) {
            const float yv = yrow[d];
            s1 += yv * Wm[d * 256 + c];
            s2 += yv * Wm[d * 256 + c + 128];
        }
        out[(size_t)n * 128 + c] = x[(size_t)n * 128 + c] * tanhf(s1) + tanhf(s2);
    }
}

// ---------------------------------------------------------------------------
extern "C" void kernel_launch(void* const* d_in, const int* in_sizes, int n_in,
                              void* d_out, int out_size, void* d_ws, size_t ws_size,
                              hipStream_t stream) {
    const float* x     = (const float*)d_in[0];
    const float* t     = (const float*)d_in[1];
    const int*   ei    = (const int*)  d_in[2];
    const float* ew    = (const float*)d_in[3];
    const float* Wq    = (const float*)d_in[4];
    const float* bq    = (const float*)d_in[5];
    const float* Wk    = (const float*)d_in[6];
    const float* bk    = (const float*)d_in[7];
    const float* Wv    = (const float*)d_in[8];
    const float* bv    = (const float*)d_in[9];
    const float* We    = (const float*)d_in[10];
    const float* be    = (const float*)d_in[11];
    const float* Wskip = (const float*)d_in[12];
    const float* bskip = (const float*)d_in[13];
    const float* Wmlp  = (const float*)d_in[14];
    const float* bmlp  = (const float*)d_in[15];

    char* p = (char*)d_ws;
    unsigned short* Qb  = (unsigned short*)p; p += (size_t)NNODES * 128 * 2;
    unsigned short* KVb = (unsigned short*)p; p += (size_t)NNODES * 256 * 2;
    float* S       = (float*)p; p += (size_t)NNODES * 32 * 4;
    float* G       = (float*)p; p += (size_t)NNODES * 32 * 4;
    unsigned short* Wtf = (unsigned short*)p; p += 416 * 256 * 2;
    float* biascat = (float*)p; p += 416 * 4;
    unsigned short* y0f = (unsigned short*)p; p += (size_t)NPAD * 256 * 2;
    int2* einfo    = (int2*)p;  p += (size_t)NNODES * CAP * 8;
    int* cnt       = (int*)p;   p += NNODES * 4;

    hipMemsetAsync(cnt, 0, (size_t)NNODES * sizeof(int), stream);

    prep_w<<<416, 256, 0, stream>>>(Wq, bq, Wk, bk, Wv, bv, Wskip, bskip,
                                    Wtf, biascat);

    pack_a<<<(NPAD * 32) / 256, 256, 0, stream>>>(x, t, y0f);

    scatter_fill<<<NEDGES / 256, 256, 0, stream>>>(ei, ew, cnt, einfo);

    dim3 gg(NPAD / 128, 4);
    gemm_mfma<<<gg, 256, 0, stream>>>(y0f, Wtf, biascat, Qb, KVb, S);

    agg_pass<<<(NNODES + 3) / 4, 256, 0, stream>>>(cnt, einfo, We, be, Qb, KVb, G);

    node_pass<<<(NNODES + 63) / 64, 256, 0, stream>>>(x, G, S, Wmlp, bmlp,
                                                      (float*)d_out);
}